// Round 21
// baseline (51.711 us; speedup 1.0000x reference)
//
#include <hip/hip_runtime.h>
#include <hip/hip_bf16.h>
#include <hip/hip_fp8.h>
#include <math.h>

#define BATCH 4096
#define TWO_B 8192
#define DIM 128
#define NB 16384
#define COS_EPS 1e-8f
#define LOSS_EPS 1e-6f
// 1/TEMP ; log2(e)/TEMP ; sqrt(log2(e)/TEMP) ; ln 2
#define INV_TEMP 14.285714285714286f
#define EXP2_SCALE 20.60992915555662f
#define SQRT_EXP2_SCALE 4.5398166f
#define LN2 0.6931471805599453f

#define N_NEAR 32768                // nearby positive dots
#define NTILES 2080                 // #{(I,J): 0<=I<=J<64} = 8 x 260
#define GRID 1024                   // 4 blocks/CU x 256 CU; blocks loop 2-3 tiles
#define STR 144                     // fp8 full-K row: 128 B data + 16 B pad

typedef __attribute__((ext_vector_type(8))) short bf16x8;
typedef __attribute__((ext_vector_type(4))) float f32x4;

__device__ __forceinline__ float fast_exp2(float x) {
#if __has_builtin(__builtin_amdgcn_exp2f)
  return __builtin_amdgcn_exp2f(x);
#else
  float r;
  asm("v_exp_f32 %0, %1" : "=v"(r) : "v"(x));
  return r;
#endif
}

__device__ __forceinline__ float2 bf2_to_f2(unsigned int w) {
  float2 r;
  r.x = __uint_as_float(w << 16);
  r.y = __uint_as_float(w & 0xffff0000u);
  return r;
}

// RNE float->bf16 (inputs bounded, no NaN/Inf path needed)
__device__ __forceinline__ unsigned short f2bf(float f) {
  unsigned int u = __float_as_uint(f);
  return (unsigned short)((u + 0x7fffu + ((u >> 16) & 1u)) >> 16);
}

// pack 4 floats -> 4 OCP e4m3 bytes
__device__ __forceinline__ unsigned int pk_fp8x4(float a, float b, float c, float d) {
#if __has_builtin(__builtin_amdgcn_cvt_pk_fp8_f32)
  int v = __builtin_amdgcn_cvt_pk_fp8_f32(a, b, 0, false);
  v = __builtin_amdgcn_cvt_pk_fp8_f32(c, d, v, true);
  return (unsigned int)v;
#else
  __hip_fp8_e4m3 qa(a), qb(b), qc(c), qd(d);
  return (unsigned int)qa.__x | ((unsigned int)qb.__x << 8) |
         ((unsigned int)qc.__x << 16) | ((unsigned int)qd.__x << 24);
#endif
}

// ---------------- K1: normalize -> bf16 za_n (positives) + fp8 za8 (gram); zero scalars ----------------
__global__ __launch_bounds__(256) void k_normalize(
    const float* __restrict__ z1, const float* __restrict__ z2,
    const float* __restrict__ zn,
    __hip_bfloat16* __restrict__ za_n, unsigned char* __restrict__ za8,
    float* __restrict__ inv_zn, float* __restrict__ augacc,
    float* __restrict__ out) {
  if (blockIdx.x == 0 && threadIdx.x == 0) { augacc[0] = 0.0f; out[0] = 0.0f; }
  const int wave = (blockIdx.x * blockDim.x + threadIdx.x) >> 6;
  const int lane = threadIdx.x & 63;
  const int row = wave * 2 + (lane >> 5);        // each 32-lane half owns one row
  const int e = lane & 31;                       // float4 slot within row
  if (row >= TWO_B + NB) return;
  const float* src;
  if (row < BATCH) src = z1 + (size_t)row * DIM;
  else if (row < TWO_B) src = z2 + (size_t)(row - BATCH) * DIM;
  else src = zn + (size_t)(row - TWO_B) * DIM;
  float4 v = ((const float4*)src)[e];
  float ss = v.x * v.x + v.y * v.y + v.z * v.z + v.w * v.w;
#pragma unroll
  for (int m = 1; m < 32; m <<= 1) ss += __shfl_xor(ss, m, 64);  // within 32-half
  float inv = 1.0f / fmaxf(sqrtf(ss), COS_EPS);
  if (row < TWO_B) {
    const float s = inv * SQRT_EXP2_SCALE;       // fold exp2 scale into the data
    ushort4 o;
    o.x = f2bf(v.x * s);
    o.y = f2bf(v.y * s);
    o.z = f2bf(v.z * s);
    o.w = f2bf(v.w * s);
    ((ushort4*)(za_n + (size_t)row * DIM))[e] = o;
    ((unsigned int*)(za8 + (size_t)row * DIM))[e] =
        pk_fp8x4(v.x * s, v.y * s, v.z * s, v.w * s);
  } else if (e == 0) {
    inv_zn[row - TWO_B] = inv;
  }
}

// ---------------- K2: fp8 symmetric Gram, 2-3 tiles per block (tail-balanced), fused positives ----------------
// grid: 1024 blocks; block loops tiles {b, b+1024, b+2048<2080}; 4 waves of 64x64;
// LDS 36.9 KB -> 4 blocks/CU. fp8 full-K single staging phase per tile.
__global__ __launch_bounds__(256) void k_gram(
    const unsigned char* __restrict__ za8f, const __hip_bfloat16* __restrict__ za_n,
    const float* __restrict__ zn, const float* __restrict__ inv_zn,
    float* __restrict__ part_row, float* __restrict__ part_col,
    float* __restrict__ pos_partial, float* __restrict__ augacc) {
  __shared__ char lds[2 * 128 * STR];   // A then B (full K=128 in fp8)
  char* ldsA = lds;
  char* ldsB = lds + 128 * STR;
  const int t = threadIdx.x;
  const char* za8 = (const char*)za8f;   // fp8 view; row stride 128 B

  const int w = t >> 6, lane = t & 63;
  const int wr = w & 1, wc = w >> 1;     // 2x2 waves of 64x64
  const int lhi = lane >> 4, llo = lane & 15;

  // fragment read bases (8 B per lane; everything else compile-time immediate)
  const int rdA0 = (wr * 64 + llo) * STR + lhi * 8;
  const int rdB0 = (wc * 64 + llo) * STR + lhi * 8;
  // staging: thread t writes rows (it*32 + t>>3), 16B chunk (t&7)
  const int st_row = t >> 3, st_kb = (t & 7) * 16;
  const int st_lds = st_row * STR + st_kb;

  for (int tt = blockIdx.x; tt < NTILES; tt += GRID) {
    __syncthreads();                     // prior tile's epilogue LDS reads done
    // XCD swizzle: 2080 = 8 x 260; consecutive lids share the A panel
    const int lid = (tt & 7) * 260 + (tt >> 3);
    int rem = lid, I = 0;
    while (rem >= 64 - I) { rem -= 64 - I; ++I; }
    const int J = I + rem;
    const int Ibase = I * 128, Jbase = J * 128;

    f32x4 acc[4][4];
#pragma unroll
    for (int rt = 0; rt < 4; ++rt)
#pragma unroll
      for (int ct = 0; ct < 4; ++ct) acc[rt][ct] = (f32x4)0.0f;

    // ---- stage full A and B tiles (fp8, 16 KB each) ----
#pragma unroll
    for (int it = 0; it < 4; ++it) {
      uint4 d = *(const uint4*)(za8 + (size_t)(Ibase + it * 32 + st_row) * 128 + st_kb);
      *(uint4*)(ldsA + it * 32 * STR + st_lds) = d;
    }
#pragma unroll
    for (int it = 0; it < 4; ++it) {
      uint4 d = *(const uint4*)(za8 + (size_t)(Jbase + it * 32 + st_row) * 128 + st_kb);
      *(uint4*)(ldsB + it * 32 * STR + st_lds) = d;
    }
    __syncthreads();                     // the only staging barrier

#pragma unroll
    for (int ks = 0; ks < 4; ++ks) {     // K = 4 x 32
      long af[4], bfr[4];
#pragma unroll
      for (int rt = 0; rt < 4; ++rt)
        af[rt] = *(const long*)(ldsA + rdA0 + rt * 16 * STR + ks * 32);
#pragma unroll
      for (int ct = 0; ct < 4; ++ct)
        bfr[ct] = *(const long*)(ldsB + rdB0 + ct * 16 * STR + ks * 32);
      __builtin_amdgcn_s_setprio(1);
#pragma unroll
      for (int rt = 0; rt < 4; ++rt)
#pragma unroll
        for (int ct = 0; ct < 4; ++ct)
          acc[rt][ct] = __builtin_amdgcn_mfma_f32_16x16x32_fp8_fp8(
              af[rt], bfr[ct], acc[rt][ct], 0, 0, 0);
      __builtin_amdgcn_s_setprio(0);
    }

    // aug-positive extraction: cells with col == row + BATCH live in tiles J-I == 32 (lc == lr)
    if (J - I == 32) {
      float ap = 0.0f;
#pragma unroll
      for (int rt = 0; rt < 4; ++rt) {
        const int lrb = wr * 64 + rt * 16 + lhi * 4;
#pragma unroll
        for (int ct = 0; ct < 4; ++ct) {
          const int lc = wc * 64 + ct * 16 + llo;
#pragma unroll
          for (int g = 0; g < 4; ++g)
            if (lc == lrb + g) ap += acc[rt][ct][g];
        }
      }
#pragma unroll
      for (int m = 1; m < 64; m <<= 1) ap += __shfl_xor(ap, m, 64);
      if (lane == 0) atomicAdd(augacc, ap);
    }

    // epilogue: exp2 (+ diag mask only on I==J tiles); per-tile row/col partials in LDS
    __syncthreads();                      // all MFMA LDS reads done; safe to alias lds
    float* lds_row = (float*)lds;         // [2][128] indexed [wc][localrow]
    float* lds_col = (float*)(lds + 1024);

    float cp[4] = {0.0f, 0.0f, 0.0f, 0.0f};
#pragma unroll
    for (int rt = 0; rt < 4; ++rt) {
      const int lrowb = wr * 64 + rt * 16 + lhi * 4;         // + g (local row)
      float rp[4] = {0.0f, 0.0f, 0.0f, 0.0f};
      if (I == J) {                        // block-uniform branch
#pragma unroll
        for (int ct = 0; ct < 4; ++ct) {
          const int lcol = wc * 64 + ct * 16 + llo;
#pragma unroll
          for (int g = 0; g < 4; ++g) {
            float e = fast_exp2(acc[rt][ct][g]);
            e = (lcol > lrowb + g) ? e : 0.0f;   // strict upper triangle
            rp[g] += e;
            cp[ct] += e;
          }
        }
      } else {
#pragma unroll
        for (int ct = 0; ct < 4; ++ct)
#pragma unroll
          for (int g = 0; g < 4; ++g) {
            float e = fast_exp2(acc[rt][ct][g]);
            rp[g] += e;
            cp[ct] += e;
          }
      }
#pragma unroll
      for (int g = 0; g < 4; ++g) {
        float s = rp[g];
        s += __shfl_xor(s, 1, 64);
        s += __shfl_xor(s, 2, 64);
        s += __shfl_xor(s, 4, 64);
        s += __shfl_xor(s, 8, 64);
        if (llo == 0) lds_row[wc * 128 + lrowb + g] = s;
      }
    }
#pragma unroll
    for (int ct = 0; ct < 4; ++ct) {
      float s = cp[ct];
      s += __shfl_xor(s, 16, 64);
      s += __shfl_xor(s, 32, 64);
      if (lhi == 0) lds_col[wr * 128 + wc * 64 + ct * 16 + llo] = s;
    }
    __syncthreads();
    if (t < 128)
      part_row[(size_t)(I * 64 + J) * 128 + t] = lds_row[t] + lds_row[128 + t];
    else
      part_col[(size_t)(J * 64 + I) * 128 + (t - 128)] =
          lds_col[t - 128] + lds_col[t];

    // ---- fused nearby positives: lids 0..1023, 32 dots each (4 waves x 8) ----
    if (lid < N_NEAR / 32) {
      const int sub = lane & 7;
      const int k = lid * 32 + w * 8 + (lane >> 3);
      int zr, zc;
      if (k < BATCH)                { zr = BATCH + k; zc = k; }
      else if (k < BATCH + TWO_B)   { int q = k - BATCH;             zr = q; zc = q; }
      else if (k < BATCH + 2*TWO_B) { int q = k - BATCH - TWO_B;     zr = q; zc = q + BATCH; }
      else if (k < BATCH + 3*TWO_B) { int q = k - BATCH - 2*TWO_B;   zr = q; zc = q + 2*BATCH; }
      else                          { int q = k - BATCH - 3*TWO_B;   zr = q; zc = q + 3*BATCH; }
      const uint4* aro = (const uint4*)(za_n + (size_t)zr * DIM);    // 16B = 8 bf16
      const float4* bro = (const float4*)(zn + (size_t)zc * DIM);
      float d = 0.0f;
#pragma unroll
      for (int c = 0; c < 2; ++c) {
        uint4 aw = aro[sub * 2 + c];
        float4 b0 = bro[sub * 4 + c * 2];
        float4 b1 = bro[sub * 4 + c * 2 + 1];
        float2 q2;
        q2 = bf2_to_f2(aw.x); d += q2.x * b0.x + q2.y * b0.y;
        q2 = bf2_to_f2(aw.y); d += q2.x * b0.z + q2.y * b0.w;
        q2 = bf2_to_f2(aw.z); d += q2.x * b1.x + q2.y * b1.y;
        q2 = bf2_to_f2(aw.w); d += q2.x * b1.z + q2.y * b1.w;
      }
      d += __shfl_xor(d, 1, 64);
      d += __shfl_xor(d, 2, 64);
      d += __shfl_xor(d, 4, 64);
      if (sub == 0) {
        float ds = d * inv_zn[zc] * SQRT_EXP2_SCALE;       // = sim * EXP2_SCALE
        pos_partial[k] = fminf(ds, EXP2_SCALE) * LN2;      // = min(sim,1) * INV_TEMP
      }
    }
  }
}

// ---------------- K3: wave-per-row-octet gather + fused final (atomicAdd out) ----------------
__global__ __launch_bounds__(256) void k_reduce(
    const float* __restrict__ part_row, const float* __restrict__ part_col,
    const float* __restrict__ pos_partial, const float* __restrict__ augacc,
    float* __restrict__ out) {
  const int w = threadIdx.x >> 6, lane = threadIdx.x & 63;
  float s = 0.0f;
#pragma unroll
  for (int i = 0; i < 8; ++i) {
    const int r = blockIdx.x * 32 + w * 8 + i;
    const int I = r >> 7, rr = r & 127;
    const size_t base = (size_t)(I * 64 + lane) * 128 + rr;
    float v = 0.0f;
    if (lane >= I) v += part_row[base];
    if (lane <= I) v += part_col[base];
#pragma unroll
    for (int m = 1; m < 64; m <<= 1) v += __shfl_xor(v, m, 64);
    if (lane == 0) {
      float tl = 8.0f * logf(v + LOSS_EPS);
      tl -= pos_partial[r];
      tl -= pos_partial[r + TWO_B];
      tl -= pos_partial[r + 2 * TWO_B];
      tl -= pos_partial[r + 3 * TWO_B];
      s += tl;
    }
  }
  __shared__ float red[4];
  if (lane == 0) red[w] = s;
  __syncthreads();
  if (threadIdx.x == 0) {
    float bs = red[0] + red[1] + red[2] + red[3];
    if (blockIdx.x == 0) bs -= 8.0f * LN2 * augacc[0];  // aug positives from gram
    atomicAdd(out, bs * (1.0f / 65536.0f));
  }
}

extern "C" void kernel_launch(void* const* d_in, const int* in_sizes, int n_in,
                              void* d_out, int out_size, void* d_ws, size_t ws_size,
                              hipStream_t stream) {
  const float* z1 = (const float*)d_in[0];
  const float* z2 = (const float*)d_in[1];
  const float* zn = (const float*)d_in[2];
  float* out = (float*)d_out;

  char* ws = (char*)d_ws;
  __hip_bfloat16* za_n = (__hip_bfloat16*)ws;                  // 2 MB
  float* inv_zn      = (float*)(ws + 2097152);                 // 64 KB
  float* pos_partial = (float*)(ws + 2097152 + 65536);         // 128 KB
  float* augacc      = (float*)(ws + 2097152 + 65536 + 131072);          // 4 KB slot
  float* part_row    = (float*)(ws + 2097152 + 65536 + 131072 + 4096);   // 2 MB
  float* part_col    = (float*)(ws + 2097152 + 65536 + 131072 + 4096 + 2097152); // 2 MB
  unsigned char* za8 = (unsigned char*)(ws + 2097152 + 65536 + 131072 + 4096 + 2097152 + 2097152); // 1 MB

  // K1: normalize -> bf16 + fp8 copies; zero scalars
  k_normalize<<<(TWO_B + NB) / 8, 256, 0, stream>>>(z1, z2, zn, za_n, za8,
                                                    inv_zn, augacc, out);
  // K2: fp8 gram partials (2-3 tiles/block) + fused nearby positives
  k_gram<<<GRID, 256, 0, stream>>>(za8, za_n, zn, inv_zn, part_row, part_col,
                                   pos_partial, augacc);
  // K3: gather/log/subtract + fused final scalar
  k_reduce<<<256, 256, 0, stream>>>(part_row, part_col, pos_partial, augacc, out);
}

// Round 22
// 41.924 us; speedup vs baseline: 1.2334x; 1.2334x over previous
//
#include <hip/hip_runtime.h>
#include <hip/hip_bf16.h>
#include <hip/hip_fp8.h>
#include <math.h>

#define BATCH 4096
#define TWO_B 8192
#define DIM 128
#define NB 16384
#define COS_EPS 1e-8f
#define LOSS_EPS 1e-6f
// 1/TEMP ; log2(e)/TEMP ; sqrt(log2(e)/TEMP) ; ln 2
#define INV_TEMP 14.285714285714286f
#define EXP2_SCALE 20.60992915555662f
#define SQRT_EXP2_SCALE 4.5398166f
#define LN2 0.6931471805599453f

#define N_NEAR 32768                // nearby positive dots
#define GRAM_BLOCKS 2080            // #{(I,J): 0<=I<=J<64} = 8 x 260
#define STR 144                     // fp8 full-K row: 128 B data + 16 B pad (2-way banks, imm offsets)

typedef __attribute__((ext_vector_type(8))) short bf16x8;
typedef __attribute__((ext_vector_type(4))) float f32x4;

__device__ __forceinline__ float fast_exp2(float x) {
#if __has_builtin(__builtin_amdgcn_exp2f)
  return __builtin_amdgcn_exp2f(x);
#else
  float r;
  asm("v_exp_f32 %0, %1" : "=v"(r) : "v"(x));
  return r;
#endif
}

__device__ __forceinline__ float2 bf2_to_f2(unsigned int w) {
  float2 r;
  r.x = __uint_as_float(w << 16);
  r.y = __uint_as_float(w & 0xffff0000u);
  return r;
}

// RNE float->bf16 (inputs bounded, no NaN/Inf path needed)
__device__ __forceinline__ unsigned short f2bf(float f) {
  unsigned int u = __float_as_uint(f);
  return (unsigned short)((u + 0x7fffu + ((u >> 16) & 1u)) >> 16);
}

// pack 4 floats -> 4 OCP e4m3 bytes
__device__ __forceinline__ unsigned int pk_fp8x4(float a, float b, float c, float d) {
#if __has_builtin(__builtin_amdgcn_cvt_pk_fp8_f32)
  int v = __builtin_amdgcn_cvt_pk_fp8_f32(a, b, 0, false);
  v = __builtin_amdgcn_cvt_pk_fp8_f32(c, d, v, true);
  return (unsigned int)v;
#else
  __hip_fp8_e4m3 qa(a), qb(b), qc(c), qd(d);
  return (unsigned int)qa.__x | ((unsigned int)qb.__x << 8) |
         ((unsigned int)qc.__x << 16) | ((unsigned int)qd.__x << 24);
#endif
}

// ---------------- K1: normalize -> bf16 za_n (positives) + fp8 za8 (gram); zero scalars ----------------
__global__ __launch_bounds__(256) void k_normalize(
    const float* __restrict__ z1, const float* __restrict__ z2,
    const float* __restrict__ zn,
    __hip_bfloat16* __restrict__ za_n, unsigned char* __restrict__ za8,
    float* __restrict__ inv_zn, float* __restrict__ augacc,
    float* __restrict__ out) {
  if (blockIdx.x == 0 && threadIdx.x == 0) { augacc[0] = 0.0f; out[0] = 0.0f; }
  const int wave = (blockIdx.x * blockDim.x + threadIdx.x) >> 6;
  const int lane = threadIdx.x & 63;
  const int row = wave * 2 + (lane >> 5);        // each 32-lane half owns one row
  const int e = lane & 31;                       // float4 slot within row
  if (row >= TWO_B + NB) return;
  const float* src;
  if (row < BATCH) src = z1 + (size_t)row * DIM;
  else if (row < TWO_B) src = z2 + (size_t)(row - BATCH) * DIM;
  else src = zn + (size_t)(row - TWO_B) * DIM;
  float4 v = ((const float4*)src)[e];
  float ss = v.x * v.x + v.y * v.y + v.z * v.z + v.w * v.w;
#pragma unroll
  for (int m = 1; m < 32; m <<= 1) ss += __shfl_xor(ss, m, 64);  // within 32-half
  float inv = 1.0f / fmaxf(sqrtf(ss), COS_EPS);
  if (row < TWO_B) {
    const float s = inv * SQRT_EXP2_SCALE;       // fold exp2 scale into the data
    ushort4 o;
    o.x = f2bf(v.x * s);
    o.y = f2bf(v.y * s);
    o.z = f2bf(v.z * s);
    o.w = f2bf(v.w * s);
    ((ushort4*)(za_n + (size_t)row * DIM))[e] = o;
    ((unsigned int*)(za8 + (size_t)row * DIM))[e] =
        pk_fp8x4(v.x * s, v.y * s, v.z * s, v.w * s);
  } else if (e == 0) {
    inv_zn[row - TWO_B] = inv;
  }
}

// ---------------- K2: fp8 symmetric Gram, full-K single phase, fused positives ----------------
// grid: 2080 independent blocks (XCD-swizzled); 4 waves of 64x64; LDS 36.9 KB -> 4 blocks/CU.
__global__ __launch_bounds__(256) void k_gram(
    const unsigned char* __restrict__ za8f, const __hip_bfloat16* __restrict__ za_n,
    const float* __restrict__ zn, const float* __restrict__ inv_zn,
    float* __restrict__ part_row, float* __restrict__ part_col,
    float* __restrict__ pos_partial, float* __restrict__ augacc) {
  __shared__ char lds[2 * 128 * STR];   // A then B (full K=128 in fp8)
  char* ldsA = lds;
  char* ldsB = lds + 128 * STR;
  const int t = threadIdx.x;
  // XCD swizzle: 2080 = 8 x 260; consecutive lids share the A panel -> per-XCD L2 locality
  const int lid = ((int)blockIdx.x & 7) * 260 + ((int)blockIdx.x >> 3);
  int rem = lid, I = 0;
  while (rem >= 64 - I) { rem -= 64 - I; ++I; }
  const int J = I + rem;
  const int Ibase = I * 128, Jbase = J * 128;
  const char* za8 = (const char*)za8f;   // fp8 view; row stride 128 B

  const int w = t >> 6, lane = t & 63;
  const int wr = w & 1, wc = w >> 1;     // 2x2 waves of 64x64
  const int lhi = lane >> 4, llo = lane & 15;

  // fragment read bases (8 B per lane; everything else compile-time immediate)
  const int rdA0 = (wr * 64 + llo) * STR + lhi * 8;
  const int rdB0 = (wc * 64 + llo) * STR + lhi * 8;
  // staging: thread t writes rows (it*32 + t>>3), 16B chunk (t&7)
  const int st_row = t >> 3, st_kb = (t & 7) * 16;
  const int st_lds = st_row * STR + st_kb;

  f32x4 acc[4][4];
#pragma unroll
  for (int rt = 0; rt < 4; ++rt)
#pragma unroll
    for (int ct = 0; ct < 4; ++ct) acc[rt][ct] = (f32x4)0.0f;

  // ---- stage full A and B tiles (fp8, 16 KB each) ----
#pragma unroll
  for (int it = 0; it < 4; ++it) {
    uint4 d = *(const uint4*)(za8 + (size_t)(Ibase + it * 32 + st_row) * 128 + st_kb);
    *(uint4*)(ldsA + it * 32 * STR + st_lds) = d;
  }
#pragma unroll
  for (int it = 0; it < 4; ++it) {
    uint4 d = *(const uint4*)(za8 + (size_t)(Jbase + it * 32 + st_row) * 128 + st_kb);
    *(uint4*)(ldsB + it * 32 * STR + st_lds) = d;
  }
  __syncthreads();                       // the only staging barrier

#pragma unroll
  for (int ks = 0; ks < 4; ++ks) {       // K = 4 x 32
    long af[4], bfr[4];
#pragma unroll
    for (int rt = 0; rt < 4; ++rt)
      af[rt] = *(const long*)(ldsA + rdA0 + rt * 16 * STR + ks * 32);
#pragma unroll
    for (int ct = 0; ct < 4; ++ct)
      bfr[ct] = *(const long*)(ldsB + rdB0 + ct * 16 * STR + ks * 32);
    __builtin_amdgcn_s_setprio(1);
#pragma unroll
    for (int rt = 0; rt < 4; ++rt)
#pragma unroll
      for (int ct = 0; ct < 4; ++ct)
        acc[rt][ct] = __builtin_amdgcn_mfma_f32_16x16x32_fp8_fp8(
            af[rt], bfr[ct], acc[rt][ct], 0, 0, 0);
    __builtin_amdgcn_s_setprio(0);
  }

  // aug-positive extraction: cells with col == row + BATCH live in tiles J-I == 32 (lc == lr)
  if (J - I == 32) {
    float ap = 0.0f;
#pragma unroll
    for (int rt = 0; rt < 4; ++rt) {
      const int lrb = wr * 64 + rt * 16 + lhi * 4;
#pragma unroll
      for (int ct = 0; ct < 4; ++ct) {
        const int lc = wc * 64 + ct * 16 + llo;
#pragma unroll
        for (int g = 0; g < 4; ++g)
          if (lc == lrb + g) ap += acc[rt][ct][g];
      }
    }
#pragma unroll
    for (int m = 1; m < 64; m <<= 1) ap += __shfl_xor(ap, m, 64);
    if (lane == 0) atomicAdd(augacc, ap);
  }

  // epilogue: exp2 (+ diag mask only on I==J blocks); per-block row/col partials in LDS
  __syncthreads();                        // all MFMA LDS reads done; safe to alias lds
  float* lds_row = (float*)lds;           // [2][128] indexed [wc][localrow]
  float* lds_col = (float*)(lds + 1024);  // [2][128] indexed [wr][localcol]

  float cp[4] = {0.0f, 0.0f, 0.0f, 0.0f};
#pragma unroll
  for (int rt = 0; rt < 4; ++rt) {
    const int lrowb = wr * 64 + rt * 16 + lhi * 4;           // + g (local row)
    float rp[4] = {0.0f, 0.0f, 0.0f, 0.0f};
    if (I == J) {                          // block-uniform branch
#pragma unroll
      for (int ct = 0; ct < 4; ++ct) {
        const int lcol = wc * 64 + ct * 16 + llo;
#pragma unroll
        for (int g = 0; g < 4; ++g) {
          float e = fast_exp2(acc[rt][ct][g]);
          e = (lcol > lrowb + g) ? e : 0.0f;   // strict upper triangle
          rp[g] += e;
          cp[ct] += e;
        }
      }
    } else {
#pragma unroll
      for (int ct = 0; ct < 4; ++ct)
#pragma unroll
        for (int g = 0; g < 4; ++g) {
          float e = fast_exp2(acc[rt][ct][g]);
          rp[g] += e;
          cp[ct] += e;
        }
    }
#pragma unroll
    for (int g = 0; g < 4; ++g) {
      float s = rp[g];
      s += __shfl_xor(s, 1, 64);
      s += __shfl_xor(s, 2, 64);
      s += __shfl_xor(s, 4, 64);
      s += __shfl_xor(s, 8, 64);
      if (llo == 0) lds_row[wc * 128 + lrowb + g] = s;
    }
  }
#pragma unroll
  for (int ct = 0; ct < 4; ++ct) {
    float s = cp[ct];
    s += __shfl_xor(s, 16, 64);
    s += __shfl_xor(s, 32, 64);
    if (lhi == 0) lds_col[wr * 128 + wc * 64 + ct * 16 + llo] = s;
  }
  __syncthreads();
  if (t < 128)
    part_row[(size_t)(I * 64 + J) * 128 + t] = lds_row[t] + lds_row[128 + t];
  else
    part_col[(size_t)(J * 64 + I) * 128 + (t - 128)] =
        lds_col[t - 128] + lds_col[t];

  // ---- fused nearby positives: lids 0..1023, 32 dots each (4 waves x 8), bf16 x fp32 exact path ----
  if (lid < N_NEAR / 32) {
    const int sub = lane & 7;
    const int k = lid * 32 + w * 8 + (lane >> 3);
    int zr, zc;
    if (k < BATCH)                { zr = BATCH + k; zc = k; }
    else if (k < BATCH + TWO_B)   { int q = k - BATCH;             zr = q; zc = q; }
    else if (k < BATCH + 2*TWO_B) { int q = k - BATCH - TWO_B;     zr = q; zc = q + BATCH; }
    else if (k < BATCH + 3*TWO_B) { int q = k - BATCH - 2*TWO_B;   zr = q; zc = q + 2*BATCH; }
    else                          { int q = k - BATCH - 3*TWO_B;   zr = q; zc = q + 3*BATCH; }
    const uint4* aro = (const uint4*)(za_n + (size_t)zr * DIM);    // 16B = 8 bf16
    const float4* bro = (const float4*)(zn + (size_t)zc * DIM);
    float d = 0.0f;
#pragma unroll
    for (int c = 0; c < 2; ++c) {
      uint4 aw = aro[sub * 2 + c];
      float4 b0 = bro[sub * 4 + c * 2];
      float4 b1 = bro[sub * 4 + c * 2 + 1];
      float2 q2;
      q2 = bf2_to_f2(aw.x); d += q2.x * b0.x + q2.y * b0.y;
      q2 = bf2_to_f2(aw.y); d += q2.x * b0.z + q2.y * b0.w;
      q2 = bf2_to_f2(aw.z); d += q2.x * b1.x + q2.y * b1.y;
      q2 = bf2_to_f2(aw.w); d += q2.x * b1.z + q2.y * b1.w;
    }
    d += __shfl_xor(d, 1, 64);
    d += __shfl_xor(d, 2, 64);
    d += __shfl_xor(d, 4, 64);
    if (sub == 0) {
      float ds = d * inv_zn[zc] * SQRT_EXP2_SCALE;       // = sim * EXP2_SCALE
      pos_partial[k] = fminf(ds, EXP2_SCALE) * LN2;      // = min(sim,1) * INV_TEMP
    }
  }
}

// ---------------- K3: wave-per-row-octet gather + fused final (atomicAdd out) ----------------
__global__ __launch_bounds__(256) void k_reduce(
    const float* __restrict__ part_row, const float* __restrict__ part_col,
    const float* __restrict__ pos_partial, const float* __restrict__ augacc,
    float* __restrict__ out) {
  const int w = threadIdx.x >> 6, lane = threadIdx.x & 63;
  float s = 0.0f;
#pragma unroll
  for (int i = 0; i < 8; ++i) {
    const int r = blockIdx.x * 32 + w * 8 + i;
    const int I = r >> 7, rr = r & 127;
    const size_t base = (size_t)(I * 64 + lane) * 128 + rr;
    float v = 0.0f;
    if (lane >= I) v += part_row[base];
    if (lane <= I) v += part_col[base];
#pragma unroll
    for (int m = 1; m < 64; m <<= 1) v += __shfl_xor(v, m, 64);
    if (lane == 0) {
      float tl = 8.0f * logf(v + LOSS_EPS);
      tl -= pos_partial[r];
      tl -= pos_partial[r + TWO_B];
      tl -= pos_partial[r + 2 * TWO_B];
      tl -= pos_partial[r + 3 * TWO_B];
      s += tl;
    }
  }
  __shared__ float red[4];
  if (lane == 0) red[w] = s;
  __syncthreads();
  if (threadIdx.x == 0) {
    float bs = red[0] + red[1] + red[2] + red[3];
    if (blockIdx.x == 0) bs -= 8.0f * LN2 * augacc[0];  // aug positives from gram
    atomicAdd(out, bs * (1.0f / 65536.0f));
  }
}

extern "C" void kernel_launch(void* const* d_in, const int* in_sizes, int n_in,
                              void* d_out, int out_size, void* d_ws, size_t ws_size,
                              hipStream_t stream) {
  const float* z1 = (const float*)d_in[0];
  const float* z2 = (const float*)d_in[1];
  const float* zn = (const float*)d_in[2];
  float* out = (float*)d_out;

  char* ws = (char*)d_ws;
  __hip_bfloat16* za_n = (__hip_bfloat16*)ws;                  // 2 MB
  float* inv_zn      = (float*)(ws + 2097152);                 // 64 KB
  float* pos_partial = (float*)(ws + 2097152 + 65536);         // 128 KB
  float* augacc      = (float*)(ws + 2097152 + 65536 + 131072);          // 4 KB slot
  float* part_row    = (float*)(ws + 2097152 + 65536 + 131072 + 4096);   // 2 MB
  float* part_col    = (float*)(ws + 2097152 + 65536 + 131072 + 4096 + 2097152); // 2 MB
  unsigned char* za8 = (unsigned char*)(ws + 2097152 + 65536 + 131072 + 4096 + 2097152 + 2097152); // 1 MB

  // K1: normalize -> bf16 + fp8 copies; zero scalars
  k_normalize<<<(TWO_B + NB) / 8, 256, 0, stream>>>(z1, z2, zn, za_n, za8,
                                                    inv_zn, augacc, out);
  // K2: fp8 gram partials + fused nearby positives
  k_gram<<<GRAM_BLOCKS, 256, 0, stream>>>(za8, za_n, zn, inv_zn, part_row, part_col,
                                          pos_partial, augacc);
  // K3: gather/log/subtract + fused final scalar
  k_reduce<<<256, 256, 0, stream>>>(part_row, part_col, pos_partial, augacc, out);
}